// Round 5
// baseline (191.477 us; speedup 1.0000x reference)
//
#include <hip/hip_runtime.h>
#include <hip/hip_cooperative_groups.h>
#include <math.h>

namespace cg = cooperative_groups;

// Problem constants: L=4096, B=4, D=1024, N=16
#define D_SZ 1024
#define CH 4096          // B*D channels
#define ROW 4096         // x stride between consecutive l (floats)
#define C_CHUNKS 64
#define LC 64            // L / C_CHUNKS
#define SUB 16           // l-rows per LDS sub-tile
#define NSUB (LC / SUB)  // 4 sub-tiles per chunk
#define TILE_F (SUB * 256)   // floats per sub-tile buffer (4096 = 16 KB)

// ---------------------------------------------------------------------------
// Param helpers: q = 1 - sigmoid(delta)*sigmoid(alpha); w = sigmoid(delta)*beta*gamma*0.25
// ---------------------------------------------------------------------------
__device__ __forceinline__ void load16(const float* __restrict__ p, int d, float v[16]) {
    const float4* p4 = (const float4*)(p + (size_t)d * 16);
#pragma unroll
    for (int r = 0; r < 4; ++r) {
        float4 t = p4[r];
        v[4*r+0] = t.x; v[4*r+1] = t.y; v[4*r+2] = t.z; v[4*r+3] = t.w;
    }
}

__device__ __forceinline__ void compute_qw(const float* __restrict__ delta,
                                           const float* __restrict__ alpha,
                                           const float* __restrict__ beta,
                                           const float* __restrict__ gamma,
                                           int d, float q[16], float w[16]) {
    float dl[16], al[16], bt[16], gm[16];
    load16(delta, d, dl); load16(alpha, d, al);
    load16(beta, d, bt);  load16(gamma, d, gm);
#pragma unroll
    for (int n = 0; n < 16; ++n) {
        float p  = 1.0f / (1.0f + __expf(-dl[n]));
        float sa = 1.0f / (1.0f + __expf(-al[n]));
        q[n] = 1.0f - p * sa;
        w[n] = p * bt[n] * gm[n] * 0.25f;   // scale = 1/sqrt(16)
    }
}

// ---------------------------------------------------------------------------
// Staging: sub-tile [SUB l x 256 ch] via 4 float4 loads/thread (16B/lane).
// Thread t, load k: l = (t>>6) + 4k, float4-col c4 = t&63.
// ---------------------------------------------------------------------------
__device__ __forceinline__ void stage_issue(const float* __restrict__ x,
                                            size_t rowBase, int tid, float4 r[4]) {
    const float* p = x + rowBase + (size_t)(tid >> 6) * ROW + ((tid & 63) << 2);
#pragma unroll
    for (int k = 0; k < 4; ++k)
        r[k] = *(const float4*)(p + (size_t)(4 * k) * ROW);
}

__device__ __forceinline__ void stage_commit(float* __restrict__ buf, int tid,
                                             const float4 r[4]) {
#pragma unroll
    for (int k = 0; k < 4; ++k)
        *(float4*)(buf + ((tid >> 6) + 4 * k) * 256 + ((tid & 63) << 2)) = r[k];
}

// ---------------------------------------------------------------------------
// Phase 1: chunk-local end state (h from 0), x staged through LDS.
// S layout: S[(j*CH + c)*16 + n]
// ---------------------------------------------------------------------------
__device__ __forceinline__ void phase1_body(const float* __restrict__ x, float* __restrict__ S,
    const float* __restrict__ delta, const float* __restrict__ alpha,
    const float* __restrict__ beta, const float* __restrict__ gamma,
    int j, int cgrp, int tid, float* __restrict__ lds) {
    int c = cgrp * 256 + tid;
    int d = c & (D_SZ - 1);
    float q[16], w[16];
    compute_qw(delta, alpha, beta, gamma, d, q, w);   // w dead -> DCE
    float h[16];
#pragma unroll
    for (int n = 0; n < 16; ++n) h[n] = 0.0f;

    size_t rb = (size_t)(j * LC) * ROW + (size_t)cgrp * 256;
    float4 r[4];
    stage_issue(x, rb, tid, r);
    stage_commit(lds, tid, r);                        // buffer 0
    for (int st = 0; st < NSUB; ++st) {
        if (st + 1 < NSUB) stage_issue(x, rb + (size_t)((st + 1) * SUB) * ROW, tid, r);
        __syncthreads();                              // commits to buf[st&1] visible
        const float* cb = lds + (st & 1) * TILE_F;
#pragma unroll
        for (int l = 0; l < SUB; ++l) {
            float xu = cb[l * 256 + tid];
#pragma unroll
            for (int n = 0; n < 16; ++n) h[n] = fmaf(q[n], h[n], xu);
        }
        if (st + 1 < NSUB) stage_commit(lds + ((st + 1) & 1) * TILE_F, tid, r);
    }
    float4* Sp = (float4*)(S + ((size_t)j * CH + c) * 16);
#pragma unroll
    for (int rr = 0; rr < 4; ++rr)
        Sp[rr] = make_float4(h[4*rr], h[4*rr+1], h[4*rr+2], h[4*rr+3]);
}

// ---------------------------------------------------------------------------
// Phase 2: wave-parallel Kogge-Stone scan over chunks. One wave per channel,
// lane = chunk j. Rewrites S with the carry-IN state per chunk.
// ---------------------------------------------------------------------------
__device__ __forceinline__ void phase2_body(float* __restrict__ S,
    const float* __restrict__ delta, const float* __restrict__ alpha, int c2, int lane) {
    int d = c2 & (D_SZ - 1);
    float dl[16], al[16];
    load16(delta, d, dl); load16(alpha, d, al);
    float pw[16];
#pragma unroll
    for (int n = 0; n < 16; ++n) {
        float p  = 1.0f / (1.0f + __expf(-dl[n]));
        float sa = 1.0f / (1.0f + __expf(-al[n]));
        float qn = 1.0f - p * sa;
#pragma unroll
        for (int t = 0; t < 6; ++t) qn *= qn;   // q^64 = q^LC
        pw[n] = qn;
    }
    float hh[16];
    float4* Sp = (float4*)(S + ((size_t)lane * CH + c2) * 16);
#pragma unroll
    for (int rr = 0; rr < 4; ++rr) {
        float4 t = Sp[rr];
        hh[4*rr] = t.x; hh[4*rr+1] = t.y; hh[4*rr+2] = t.z; hh[4*rr+3] = t.w;
    }
#pragma unroll
    for (int k = 1; k <= 32; k <<= 1) {
        float prev[16];
#pragma unroll
        for (int n = 0; n < 16; ++n) prev[n] = __shfl_up(hh[n], (unsigned)k, 64);
#pragma unroll
        for (int n = 0; n < 16; ++n) hh[n] = (lane >= k) ? fmaf(pw[n], prev[n], hh[n]) : hh[n];
#pragma unroll
        for (int n = 0; n < 16; ++n) pw[n] *= pw[n];
    }
    float cin[16];
#pragma unroll
    for (int n = 0; n < 16; ++n) {
        float t = __shfl_up(hh[n], 1u, 64);
        cin[n] = (lane == 0) ? 0.0f : t;
    }
#pragma unroll
    for (int rr = 0; rr < 4; ++rr)
        Sp[rr] = make_float4(cin[4*rr], cin[4*rr+1], cin[4*rr+2], cin[4*rr+3]);
}

// ---------------------------------------------------------------------------
// Phase 3: recurrence seeded with carry-in; out = silu(sum_n w_n h_n + x*omega)
// x staged through LDS (same pipeline as phase 1).
// ---------------------------------------------------------------------------
__device__ __forceinline__ void phase3_body(const float* __restrict__ x,
    const float* __restrict__ S, float* __restrict__ out,
    const float* __restrict__ delta, const float* __restrict__ alpha,
    const float* __restrict__ beta, const float* __restrict__ gamma,
    const float* __restrict__ omega, int j, int cgrp, int tid, float* __restrict__ lds) {
    int c = cgrp * 256 + tid;
    int d = c & (D_SZ - 1);
    float q[16], w[16];
    compute_qw(delta, alpha, beta, gamma, d, q, w);
    float om = omega[d];
    float h[16];
    const float4* Sp = (const float4*)(S + ((size_t)j * CH + c) * 16);
#pragma unroll
    for (int rr = 0; rr < 4; ++rr) {
        float4 t = Sp[rr];
        h[4*rr] = t.x; h[4*rr+1] = t.y; h[4*rr+2] = t.z; h[4*rr+3] = t.w;
    }

    size_t rb = (size_t)(j * LC) * ROW + (size_t)cgrp * 256;
    float4 r[4];
    stage_issue(x, rb, tid, r);
    stage_commit(lds, tid, r);
    for (int st = 0; st < NSUB; ++st) {
        if (st + 1 < NSUB) stage_issue(x, rb + (size_t)((st + 1) * SUB) * ROW, tid, r);
        __syncthreads();
        const float* cb = lds + (st & 1) * TILE_F;
        size_t obase = rb + (size_t)(st * SUB) * ROW + (size_t)tid;
#pragma unroll
        for (int l = 0; l < SUB; ++l) {
            float xu = cb[l * 256 + tid];
            float y0 = 0.0f, y1 = 0.0f, y2 = 0.0f, y3 = 0.0f;
#pragma unroll
            for (int n = 0; n < 16; n += 4) {
                h[n]   = fmaf(q[n],   h[n],   xu); y0 = fmaf(w[n],   h[n],   y0);
                h[n+1] = fmaf(q[n+1], h[n+1], xu); y1 = fmaf(w[n+1], h[n+1], y1);
                h[n+2] = fmaf(q[n+2], h[n+2], xu); y2 = fmaf(w[n+2], h[n+2], y2);
                h[n+3] = fmaf(q[n+3], h[n+3], xu); y3 = fmaf(w[n+3], h[n+3], y3);
            }
            float z = (y0 + y1) + (y2 + y3) + xu * om;
            float res = z / (1.0f + __expf(-z));   // silu
            __builtin_nontemporal_store(res, &out[obase + (size_t)l * ROW]);
        }
        if (st + 1 < NSUB) stage_commit(lds + ((st + 1) & 1) * TILE_F, tid, r);
    }
}

// ---------------------------------------------------------------------------
// Fused cooperative kernel: 1024 blocks x 256 thr, 32 KB LDS -> 4 blocks/CU.
// ---------------------------------------------------------------------------
__global__ __launch_bounds__(256, 4) void ema_fused(
    const float* __restrict__ x, const float* __restrict__ delta,
    const float* __restrict__ alpha, const float* __restrict__ beta,
    const float* __restrict__ gamma, const float* __restrict__ omega,
    float* __restrict__ S, float* __restrict__ out) {
    __shared__ float lds[2 * TILE_F];
    int tid = threadIdx.x;
    int j = blockIdx.x;                    // chunk
    int cgrp = blockIdx.y;                 // channel group (256 ch)
    phase1_body(x, S, delta, alpha, beta, gamma, j, cgrp, tid, lds);
    cg::this_grid().sync();
    int gb = cgrp * gridDim.x + j;         // 0..1023
    phase2_body(S, delta, alpha, gb * 4 + (tid >> 6), tid & 63);
    cg::this_grid().sync();
    phase3_body(x, S, out, delta, alpha, beta, gamma, omega, j, cgrp, tid, lds);
}

// Fallback (non-cooperative) pipeline — same device code, 3 dispatches.
__global__ __launch_bounds__(256) void k_phase1(const float* __restrict__ x, float* __restrict__ S,
    const float* __restrict__ delta, const float* __restrict__ alpha,
    const float* __restrict__ beta, const float* __restrict__ gamma) {
    __shared__ float lds[2 * TILE_F];
    phase1_body(x, S, delta, alpha, beta, gamma, blockIdx.x, blockIdx.y, threadIdx.x, lds);
}
__global__ __launch_bounds__(256) void k_phase2(float* __restrict__ S,
    const float* __restrict__ delta, const float* __restrict__ alpha) {
    phase2_body(S, delta, alpha, blockIdx.x * 4 + (threadIdx.x >> 6), threadIdx.x & 63);
}
__global__ __launch_bounds__(256) void k_phase3(const float* __restrict__ x,
    const float* __restrict__ S, float* __restrict__ out,
    const float* __restrict__ delta, const float* __restrict__ alpha,
    const float* __restrict__ beta, const float* __restrict__ gamma,
    const float* __restrict__ omega) {
    __shared__ float lds[2 * TILE_F];
    phase3_body(x, S, out, delta, alpha, beta, gamma, omega,
                blockIdx.x, blockIdx.y, threadIdx.x, lds);
}

// ---------------------------------------------------------------------------
extern "C" void kernel_launch(void* const* d_in, const int* in_sizes, int n_in,
                              void* d_out, int out_size, void* d_ws, size_t ws_size,
                              hipStream_t stream) {
    const float* x     = (const float*)d_in[0];
    const float* delta = (const float*)d_in[1];
    const float* alpha = (const float*)d_in[2];
    const float* beta  = (const float*)d_in[3];
    const float* gamma = (const float*)d_in[4];
    const float* omega = (const float*)d_in[5];
    float* out = (float*)d_out;
    float* S   = (float*)d_ws;             // 64*4096*16*4B = 16.8 MB

    dim3 grid(C_CHUNKS, CH / 256);         // (64,16) = 1024 blocks

    int maxBlocks = 0;
    hipError_t e = hipOccupancyMaxActiveBlocksPerMultiprocessor(
        &maxBlocks, (const void*)ema_fused, 256, 0);
    if (e == hipSuccess && maxBlocks >= 4) {
        void* args[] = {(void*)&x, (void*)&delta, (void*)&alpha, (void*)&beta,
                        (void*)&gamma, (void*)&omega, (void*)&S, (void*)&out};
        hipLaunchCooperativeKernel((const void*)ema_fused, grid, dim3(256, 1, 1),
                                   args, 0, stream);
    } else {
        k_phase1<<<grid, 256, 0, stream>>>(x, S, delta, alpha, beta, gamma);
        k_phase2<<<CH / 4, 256, 0, stream>>>(S, delta, alpha);
        k_phase3<<<grid, 256, 0, stream>>>(x, S, out, delta, alpha, beta, gamma, omega);
    }
}